// Round 1
// baseline (924.067 us; speedup 1.0000x reference)
//
#include <hip/hip_runtime.h>
#include <cstddef>

#define BATCH   32768
#define IN_DIM  1024
#define ROW_F4  768        // 3072 floats / 4 per x row
#define EMBED   16
#define TINY    16
#define OUT     1000
#define NE      4
#define KHW     68         // 64 gated-hidden + 4 gate values

#define K1_GRID   512
#define K1_BLOCK  512      // 8 waves
#define K1_ROWS   (BATCH / (K1_GRID * 8))   // 8 rows per wave

#define K2_GRID   1024
#define K2_BLOCK  256
#define K2_ROWS_PER_BLOCK (BATCH / (K2_GRID / 4))   // 128
#define K2_CHUNK  64

// ---------------------------------------------------------------------------
// Kernel 1: per row -> e = relu(x[:1024] @ We^T + be); gate = softmax(e@Wg^T+bg)
// h = relu(e @ W1 + b1); store hw[b][i*16+t] = gate_i * h_{i,t}; hw[b][64+i]=gate_i
// One wave per row. W_embed staged in LDS (64 KB). Full butterfly reduce so
// every lane holds all 16 e values; lane l = expert(l>>4), hidden(l&15).
// ---------------------------------------------------------------------------
__global__ __launch_bounds__(K1_BLOCK, 4) void k_embed(
    const float* __restrict__ x, const float* __restrict__ W_embed,
    const float* __restrict__ b_embed, const float* __restrict__ W1,
    const float* __restrict__ b1, const float* __restrict__ Wg,
    const float* __restrict__ bg, float* __restrict__ hw_out)
{
    __shared__ float Wl[EMBED * IN_DIM];   // 64 KB
    const int tid = threadIdx.x;

    {   // stage W_embed (coalesced float4)
        const float4* src = (const float4*)W_embed;
        float4* dst = (float4*)Wl;
        #pragma unroll
        for (int i = 0; i < (EMBED * IN_DIM / 4) / K1_BLOCK; ++i)
            dst[tid + i * K1_BLOCK] = src[tid + i * K1_BLOCK];
    }
    __syncthreads();

    const int lane = tid & 63;
    const int wave = tid >> 6;
    const int wave_global = blockIdx.x * (K1_BLOCK / 64) + wave;
    const int r0 = wave_global * K1_ROWS;

    const int i_e = lane >> 4;   // expert index 0..3
    const int t_e = lane & 15;   // hidden index 0..15

    // per-block register preloads (tiny weights)
    float wgr[EMBED], w1r[EMBED], be[EMBED];
    #pragma unroll
    for (int j = 0; j < EMBED; ++j) {
        wgr[j] = Wg[i_e * EMBED + j];
        w1r[j] = W1[i_e * (EMBED * TINY) + j * TINY + t_e];
        be[j]  = b_embed[j];
    }
    const float b1r = b1[lane];     // [4,16] flat == lane
    const float bgr = bg[i_e];

    const float4* xv = (const float4*)x;

    // prefetch first row: 4 x float4 per lane = 4 KB per wave
    float4 cur[4];
    int r = r0;
    #pragma unroll
    for (int it = 0; it < 4; ++it)
        cur[it] = xv[(size_t)r * ROW_F4 + it * 64 + lane];

    for (int ri = 0; ri < K1_ROWS; ++ri) {
        float4 nxt[4];
        const int rn = r + 1;
        if (ri + 1 < K1_ROWS) {
            #pragma unroll
            for (int it = 0; it < 4; ++it)
                nxt[it] = xv[(size_t)rn * ROW_F4 + it * 64 + lane];
        }

        float acc[EMBED];
        #pragma unroll
        for (int j = 0; j < EMBED; ++j) acc[j] = 0.f;

        #pragma unroll
        for (int it = 0; it < 4; ++it) {
            const float4 x4 = cur[it];
            #pragma unroll
            for (int j = 0; j < EMBED; ++j) {
                const float4 w4 =
                    ((const float4*)(Wl + j * IN_DIM))[it * 64 + lane];
                acc[j] = fmaf(x4.x, w4.x,
                         fmaf(x4.y, w4.y,
                         fmaf(x4.z, w4.z,
                         fmaf(x4.w, w4.w, acc[j]))));
            }
        }

        // butterfly reduce: every lane ends with the full sum for each j
        #pragma unroll
        for (int j = 0; j < EMBED; ++j) {
            float v = acc[j];
            v += __shfl_xor(v, 32);
            v += __shfl_xor(v, 16);
            v += __shfl_xor(v, 8);
            v += __shfl_xor(v, 4);
            v += __shfl_xor(v, 2);
            v += __shfl_xor(v, 1);
            acc[j] = v;
        }

        // e = relu(acc + b_embed)
        float e[EMBED];
        #pragma unroll
        for (int j = 0; j < EMBED; ++j) e[j] = fmaxf(acc[j] + be[j], 0.f);

        // gate logit for this lane's expert (identical within 16-lane group)
        float g = bgr;
        #pragma unroll
        for (int j = 0; j < EMBED; ++j) g = fmaf(e[j], wgr[j], g);
        float mx = g;
        mx = fmaxf(mx, __shfl_xor(mx, 16));
        mx = fmaxf(mx, __shfl_xor(mx, 32));
        float ex = __expf(g - mx);
        float s = ex;
        s += __shfl_xor(s, 16);
        s += __shfl_xor(s, 32);
        const float gate = ex / s;

        // h_{i,t} then gated
        float h = b1r;
        #pragma unroll
        for (int j = 0; j < EMBED; ++j) h = fmaf(e[j], w1r[j], h);
        h = fmaxf(h, 0.f);

        float* wsrow = hw_out + (size_t)r * KHW;
        wsrow[lane] = gate * h;
        if (t_e == 0) wsrow[64 + i_e] = gate;

        r = rn;
        #pragma unroll
        for (int it = 0; it < 4; ++it) cur[it] = nxt[it];
    }
}

// ---------------------------------------------------------------------------
// Kernel 2: out[b, :] = hw[b, 0:68] @ Wcat[68, 1000]
// where Wcat[k<64] = W2[k>>4, k&15, :] and Wcat[64+i] = b2[i, :].
// Thread owns one output column (68 W values in registers); hw rows staged in
// LDS, read as wave-uniform float4 broadcasts. blockIdx: low 2 bits = col tile.
// ---------------------------------------------------------------------------
__global__ __launch_bounds__(K2_BLOCK) void k_out(
    const float* __restrict__ hw, const float* __restrict__ W2,
    const float* __restrict__ b2, float* __restrict__ out)
{
    __shared__ float hl[K2_CHUNK * KHW];   // 17408 B
    const int tid = threadIdx.x;
    const int col_tile = blockIdx.x & 3;
    const int row_blk  = blockIdx.x >> 2;
    const int c = col_tile * K2_BLOCK + tid;
    const bool valid = c < OUT;
    const int cc = valid ? c : (OUT - 1);

    float w[KHW];
    #pragma unroll
    for (int k = 0; k < 64; ++k)
        w[k] = W2[(size_t)(k >> 4) * (TINY * OUT) + (k & 15) * OUT + cc];
    #pragma unroll
    for (int i = 0; i < NE; ++i) w[64 + i] = b2[(size_t)i * OUT + cc];

    const int r0 = row_blk * K2_ROWS_PER_BLOCK;

    for (int rc = 0; rc < K2_ROWS_PER_BLOCK; rc += K2_CHUNK) {
        __syncthreads();   // protect previous chunk's readers
        {
            const float4* src = (const float4*)(hw + (size_t)(r0 + rc) * KHW);
            float4* dst = (float4*)hl;
            for (int i = tid; i < K2_CHUNK * KHW / 4; i += K2_BLOCK)
                dst[i] = src[i];
        }
        __syncthreads();

        for (int rr = 0; rr < K2_CHUNK; ++rr) {
            const float4* hrow = (const float4*)(hl + rr * KHW);
            float a0 = 0.f, a1 = 0.f, a2 = 0.f, a3 = 0.f;
            #pragma unroll
            for (int kk = 0; kk < KHW / 4; ++kk) {
                const float4 h4 = hrow[kk];   // broadcast, conflict-free
                a0 = fmaf(h4.x, w[4 * kk + 0], a0);
                a1 = fmaf(h4.y, w[4 * kk + 1], a1);
                a2 = fmaf(h4.z, w[4 * kk + 2], a2);
                a3 = fmaf(h4.w, w[4 * kk + 3], a3);
            }
            if (valid)
                out[(size_t)(r0 + rc + rr) * OUT + c] = (a0 + a1) + (a2 + a3);
        }
    }
}

extern "C" void kernel_launch(void* const* d_in, const int* in_sizes, int n_in,
                              void* d_out, int out_size, void* d_ws, size_t ws_size,
                              hipStream_t stream) {
    const float* x       = (const float*)d_in[0];
    const float* W_embed = (const float*)d_in[1];
    const float* b_embed = (const float*)d_in[2];
    const float* W1      = (const float*)d_in[3];
    const float* b1      = (const float*)d_in[4];
    const float* W2      = (const float*)d_in[5];
    const float* b2      = (const float*)d_in[6];
    const float* Wg      = (const float*)d_in[7];
    const float* bg      = (const float*)d_in[8];
    float* out = (float*)d_out;
    float* hw  = (float*)d_ws;   // BATCH * 68 floats = 8.9 MB

    k_embed<<<K1_GRID, K1_BLOCK, 0, stream>>>(x, W_embed, b_embed, W1, b1,
                                              Wg, bg, hw);
    k_out<<<K2_GRID, K2_BLOCK, 0, stream>>>(hw, W2, b2, out);
}

// Round 2
// 542.906 us; speedup vs baseline: 1.7021x; 1.7021x over previous
//
#include <hip/hip_runtime.h>
#include <cstddef>
#include <cstdint>

typedef short short8 __attribute__((ext_vector_type(8)));
typedef float floatx4 __attribute__((ext_vector_type(4)));

#define BATCH   32768
#define IN_DIM  1024
#define ROW_F   3072      // floats per x row (3*32*32)
#define EMBED   16
#define TINY    16
#define OUT     1000
#define NE      4
#define KPAD    96        // hw row: 64 gated-h + 4 gates + 28 zeros (bf16)
#define NT_N    63        // ceil(1000/16) column tiles

#define HW_BYTES ((size_t)BATCH * KPAD * 2)          // 6291456
#define BF_BYTES ((size_t)NT_N * 3 * 64 * 8 * 2)     // 193536
#define WEF_SHORTS (32 * 64 * 8 * 2)                 // hi + lo = 32768

__device__ __forceinline__ unsigned short f2bf_rne(float f) {
    unsigned u = __builtin_bit_cast(unsigned, f);
    return (unsigned short)((u + 0x7FFFu + ((u >> 16) & 1u)) >> 16);
}

// ---------------------------------------------------------------------------
// Prep: pack Wcat[96x1000] (W2 rows, b2 rows, zero pad) into B-fragment order
// for 16x16x32 bf16 MFMA, and W_embed into hi/lo bf16 B-fragment order.
// B-frag element: lane holds B[k = s*32 + (lane>>4)*8 + i][n = ntile*16 + (lane&15)]
// ---------------------------------------------------------------------------
__global__ void k_prep(const float* __restrict__ W2, const float* __restrict__ b2,
                       const float* __restrict__ W_embed,
                       unsigned short* __restrict__ Bf,
                       unsigned short* __restrict__ WeF) {
    int tid = blockIdx.x * 256 + threadIdx.x;
    if (blockIdx.x < 48) {                  // Wcat fragments: 63*3*64 threads
        if (tid >= NT_N * 3 * 64) return;
        int n = tid / 192, r = tid % 192, s = r / 64, lane = r % 64;
        int col = n * 16 + (lane & 15);
        int kq = s * 32 + (lane >> 4) * 8;
        #pragma unroll
        for (int i = 0; i < 8; ++i) {
            int k = kq + i;
            float v = 0.f;
            if (col < OUT) {
                if (k < 64) v = W2[(size_t)((k >> 4) * 16 + (k & 15)) * OUT + col];
                else if (k < 68) v = b2[(size_t)(k - 64) * OUT + col];
            }
            Bf[(size_t)tid * 8 + i] = f2bf_rne(v);
        }
    } else {                                // W_embed hi/lo fragments: 32*64 threads
        int id = tid - 48 * 256;
        if (id >= 32 * 64) return;
        int s = id >> 6, lane = id & 63;
        int j = lane & 15;
        int kq = s * 32 + ((lane >> 4) << 3);
        #pragma unroll
        for (int i = 0; i < 8; ++i) {
            float w = W_embed[(size_t)j * IN_DIM + kq + i];
            unsigned u = __builtin_bit_cast(unsigned, w);
            WeF[id * 8 + i] = (unsigned short)(u >> 16);                 // hi (trunc)
            float hif = __builtin_bit_cast(float, u & 0xFFFF0000u);
            float d = w - hif;
            WeF[16384 + id * 8 + i] =
                (unsigned short)(__builtin_bit_cast(unsigned, d) >> 16); // lo
        }
    }
}

// ---------------------------------------------------------------------------
// K1: e = relu(x[:,:1024] @ We^T + be) via hi/lo-split bf16 MFMA (fp32-accurate),
// then gate = softmax(e@Wg^T+bg), h = relu(e@W1+b1); write hw rows (bf16, K=96):
// [0:64] = gate_i * h_{i,t}, [64:68] = gate, [68:96] = 0.
// One wave per 16-row tile. 512 blocks x 256 thr (4 waves) = 2048 tiles.
// ---------------------------------------------------------------------------
__global__ __launch_bounds__(256, 2) void k_embed(
    const float* __restrict__ x, const unsigned short* __restrict__ WeF,
    const float* __restrict__ b_embed, const float* __restrict__ W1,
    const float* __restrict__ b1, const float* __restrict__ Wg,
    const float* __restrict__ bg, unsigned short* __restrict__ hw)
{
    __shared__ short bb_lds[WEF_SHORTS];    // [0:16384) hi frags, [16384:) lo
    __shared__ float e_lds[4][16 * 20];     // per-wave, row stride 20 (16B-aligned)
    __shared__ float g_lds[4][64];          // per-wave gates: [i*16 + row]

    const int tid = threadIdx.x;
    {   // stage pre-packed We fragments: 64 KB coalesced copy
        const float4* src = (const float4*)WeF;
        float4* dst = (float4*)bb_lds;
        #pragma unroll
        for (int i = 0; i < 16; ++i)
            dst[tid + i * 256] = src[tid + i * 256];
    }
    __syncthreads();

    const int lane = tid & 63;
    const int wv   = tid >> 6;
    const int quad = lane >> 4;
    const int jcol = lane & 15;             // A: row-in-tile; C: embed index j
    const int tile = blockIdx.x * 4 + wv;
    const int row0 = tile * 16;

    // tiny weights into registers (used in the tail)
    const float be  = b_embed[jcol];
    const float bgr = bg[quad];             // gate phase: i = lane>>4
    float wgr[EMBED], w1r[EMBED];
    #pragma unroll
    for (int j = 0; j < EMBED; ++j) {
        wgr[j] = Wg[quad * EMBED + j];                      // Wg[i][j]
        w1r[j] = W1[(size_t)(quad * EMBED + j) * TINY + jcol]; // W1[i][j][t]
    }
    const float b1r = b1[lane];

    const short8* bhv = (const short8*)bb_lds;
    const short8* blv = (const short8*)(bb_lds + 16384);

    const float* xrow = x + (size_t)(row0 + jcol) * ROW_F + quad * 8;

    floatx4 acc0 = {0, 0, 0, 0}, acc1 = {0, 0, 0, 0};

    auto step = [&](float4 A0, float4 A1, int s) {
        float fa[8] = {A0.x, A0.y, A0.z, A0.w, A1.x, A1.y, A1.z, A1.w};
        short8 ahi, alo;
        #pragma unroll
        for (int m = 0; m < 8; ++m) {
            unsigned u = __builtin_bit_cast(unsigned, fa[m]);
            ahi[m] = (short)(u >> 16);
            float hif = __builtin_bit_cast(float, u & 0xFFFF0000u);
            float d = fa[m] - hif;
            alo[m] = (short)(__builtin_bit_cast(unsigned, d) >> 16);
        }
        short8 bh = bhv[s * 64 + lane];
        short8 bl = blv[s * 64 + lane];
        acc0 = __builtin_amdgcn_mfma_f32_16x16x32_bf16(ahi, bh, acc0, 0, 0, 0);
        acc1 = __builtin_amdgcn_mfma_f32_16x16x32_bf16(ahi, bl, acc1, 0, 0, 0);
        acc1 = __builtin_amdgcn_mfma_f32_16x16x32_bf16(alo, bh, acc1, 0, 0, 0);
    };

    // K-loop: 32 steps of K=32, software-pipelined two steps ahead
    float4 c0, c1, c2, c3, n0, n1, n2, n3;
    c0 = *(const float4*)(xrow + 0);
    c1 = *(const float4*)(xrow + 4);
    c2 = *(const float4*)(xrow + 32);
    c3 = *(const float4*)(xrow + 36);
    #pragma unroll
    for (int sp = 0; sp < 16; ++sp) {
        if (sp < 15) {
            const float* p = xrow + (sp * 2 + 2) * 32;
            n0 = *(const float4*)(p + 0);
            n1 = *(const float4*)(p + 4);
            n2 = *(const float4*)(p + 32);
            n3 = *(const float4*)(p + 36);
        }
        step(c0, c1, 2 * sp);
        step(c2, c3, 2 * sp + 1);
        c0 = n0; c1 = n1; c2 = n2; c3 = n3;
    }

    // e tile -> LDS. C layout: col(j) = lane&15, row = quad*4 + reg
    float* el = e_lds[wv];
    #pragma unroll
    for (int reg = 0; reg < 4; ++reg) {
        float e = fmaxf(acc0[reg] + acc1[reg] + be, 0.f);
        el[(quad * 4 + reg) * 20 + jcol] = e;
    }
    __syncthreads();

    // gate phase: lane -> (row = lane&15, i = lane>>4)
    {
        const int grow = lane & 15;
        float logit = bgr;
        #pragma unroll
        for (int j = 0; j < EMBED; ++j)
            logit = fmaf(el[grow * 20 + j], wgr[j], logit);
        float mx = fmaxf(logit, __shfl_xor(logit, 16));
        mx = fmaxf(mx, __shfl_xor(mx, 32));
        float ex = __expf(logit - mx);
        float sm = ex + __shfl_xor(ex, 16);
        sm = sm + __shfl_xor(sm, 32);
        g_lds[wv][lane] = ex / sm;          // g_lds[i*16 + row]
    }
    __syncthreads();

    // h phase: lane -> (i = lane>>4, t = lane&15); iterate 16 rows
    #pragma unroll
    for (int r = 0; r < 16; ++r) {
        const float4* ev = (const float4*)(el + r * 20);
        float4 e0 = ev[0], e1 = ev[1], e2 = ev[2], e3 = ev[3];
        float h = b1r;
        h = fmaf(e0.x, w1r[0],  h); h = fmaf(e0.y, w1r[1],  h);
        h = fmaf(e0.z, w1r[2],  h); h = fmaf(e0.w, w1r[3],  h);
        h = fmaf(e1.x, w1r[4],  h); h = fmaf(e1.y, w1r[5],  h);
        h = fmaf(e1.z, w1r[6],  h); h = fmaf(e1.w, w1r[7],  h);
        h = fmaf(e2.x, w1r[8],  h); h = fmaf(e2.y, w1r[9],  h);
        h = fmaf(e2.z, w1r[10], h); h = fmaf(e2.w, w1r[11], h);
        h = fmaf(e3.x, w1r[12], h); h = fmaf(e3.y, w1r[13], h);
        h = fmaf(e3.z, w1r[14], h); h = fmaf(e3.w, w1r[15], h);
        h = fmaxf(h, 0.f);
        const float gate = g_lds[wv][quad * 16 + r];
        unsigned short* orow = hw + (size_t)(row0 + r) * KPAD;
        orow[lane] = f2bf_rne(gate * h);
        if (lane < 4)        orow[64 + lane] = f2bf_rne(g_lds[wv][lane * 16 + r]);
        else if (lane < 32)  orow[64 + lane] = 0;   // zero pad k=68..95
    }
}

// ---------------------------------------------------------------------------
// K2: out[32768x1000] = hw[32768x96] @ Wcat[96x1000], bf16 MFMA 16x16x32.
// Wave owns 8 column-tiles (B-frags resident in 96 VGPRs) and loops 8 M-tiles.
// 512 blocks x 256 thr = 2048 waves; write-BW bound (131 MB out).
// ---------------------------------------------------------------------------
__global__ __launch_bounds__(256, 2) void k_out(
    const unsigned short* __restrict__ hw, const unsigned short* __restrict__ Bf,
    float* __restrict__ out)
{
    const int tid  = threadIdx.x;
    const int lane = tid & 63;
    const int wid  = blockIdx.x * 4 + (tid >> 6);   // 0..2047
    const int g      = wid & 7;
    const int mstart = wid >> 3;                    // 0..255
    const int nt0    = g * 8;
    const int NT     = (g == 7) ? 7 : 8;
    const int quad   = lane >> 4;
    const int cl     = lane & 15;

    const short8* bfv = (const short8*)Bf;
    const short8* hv  = (const short8*)hw;          // row stride 12 short8

    short8 bfrag[8][3];
    #pragma unroll
    for (int nt = 0; nt < 8; ++nt)
        if (nt < NT)
            #pragma unroll
            for (int s = 0; s < 3; ++s)
                bfrag[nt][s] = bfv[(size_t)((nt0 + nt) * 3 + s) * 64 + lane];

    int m = mstart;
    short8 a_cur[3], a_nxt[3];
    #pragma unroll
    for (int s = 0; s < 3; ++s)
        a_cur[s] = hv[(size_t)(m * 16 + cl) * 12 + s * 4 + quad];

    for (int t = 0; t < 8; ++t) {
        const int mn = m + 256;
        if (t < 7) {
            #pragma unroll
            for (int s = 0; s < 3; ++s)
                a_nxt[s] = hv[(size_t)(mn * 16 + cl) * 12 + s * 4 + quad];
        }

        floatx4 acc[8];
        #pragma unroll
        for (int nt = 0; nt < 8; ++nt) acc[nt] = (floatx4){0, 0, 0, 0};

        #pragma unroll
        for (int s = 0; s < 3; ++s)
            #pragma unroll
            for (int nt = 0; nt < 8; ++nt)
                if (nt < NT)
                    acc[nt] = __builtin_amdgcn_mfma_f32_16x16x32_bf16(
                        a_cur[s], bfrag[nt][s], acc[nt], 0, 0, 0);

        const int rowb = m * 16 + quad * 4;
        #pragma unroll
        for (int nt = 0; nt < 8; ++nt) {
            if (nt < NT) {
                const int col = (nt0 + nt) * 16 + cl;
                if (col < OUT) {
                    #pragma unroll
                    for (int reg = 0; reg < 4; ++reg)
                        out[(size_t)(rowb + reg) * OUT + col] = acc[nt][reg];
                }
            }
        }
        m = mn;
        #pragma unroll
        for (int s = 0; s < 3; ++s) a_cur[s] = a_nxt[s];
    }
}

extern "C" void kernel_launch(void* const* d_in, const int* in_sizes, int n_in,
                              void* d_out, int out_size, void* d_ws, size_t ws_size,
                              hipStream_t stream) {
    const float* x       = (const float*)d_in[0];
    const float* W_embed = (const float*)d_in[1];
    const float* b_embed = (const float*)d_in[2];
    const float* W1      = (const float*)d_in[3];
    const float* b1      = (const float*)d_in[4];
    const float* W2      = (const float*)d_in[5];
    const float* b2      = (const float*)d_in[6];
    const float* Wg      = (const float*)d_in[7];
    const float* bg      = (const float*)d_in[8];
    float* out = (float*)d_out;

    unsigned short* hw  = (unsigned short*)d_ws;
    unsigned short* Bf  = (unsigned short*)((char*)d_ws + HW_BYTES);
    unsigned short* WeF = (unsigned short*)((char*)d_ws + HW_BYTES + BF_BYTES);

    k_prep<<<56, 256, 0, stream>>>(W2, b2, W_embed, Bf, WeF);
    k_embed<<<512, 256, 0, stream>>>(x, WeF, b_embed, W1, b1, Wg, bg, hw);
    k_out<<<512, 256, 0, stream>>>(hw, Bf, out);
}